// Round 1
// baseline (483.578 us; speedup 1.0000x reference)
//
#include <hip/hip_runtime.h>
#include <cstdint>
#include <cstddef>

using u16 = unsigned short;
using u32 = unsigned int;

typedef _Float16 f16x8 __attribute__((ext_vector_type(8)));
typedef float    f32x4 __attribute__((ext_vector_type(4)));

#define MFMA16(a, b, c) __builtin_amdgcn_mfma_f32_16x16x32_f16((a), (b), (c), 0, 0, 0)

__device__ __forceinline__ u16 f2h(float f) {
  return __builtin_bit_cast(u16, (_Float16)f);
}

__device__ __forceinline__ void async16(const void* g, void* lds) {
  __builtin_amdgcn_global_load_lds((const __attribute__((address_space(1))) void*)g,
                                   (__attribute__((address_space(3))) void*)lds,
                                   16, 0, 0);
}

// ---------------- fp32 -> fp16 convert ----------------
__global__ __launch_bounds__(256) void cvt_f32_f16(const float* __restrict__ in,
                                                   u16* __restrict__ out, int n4) {
  int i = blockIdx.x * 256 + threadIdx.x;
  const int stride = gridDim.x * 256;
  for (; i < n4; i += stride) {
    const float4 f = reinterpret_cast<const float4*>(in)[i];
    ushort4 o;
    o.x = f2h(f.x); o.y = f2h(f.y); o.z = f2h(f.z); o.w = f2h(f.w);
    reinterpret_cast<ushort4*>(out)[i] = o;
  }
}

// ---------------- GEMM: C[M,N] = A[M,K] * B[N,K]^T (both f16 row-major) ----------------
// 128x128 tile, BK=64, 256 threads = 2x2 waves, each wave 64x64 out (4x4 x 16x16 frags).
// LDS layout: [row][64] f16, XOR-swizzled: 16B chunk index ^= (row&7), applied by
// pre-swizzling the *global* source chunk during global_load_lds staging.
template <int OF32>
__global__ __launch_bounds__(256) void gemm_bt(const u16* __restrict__ A,
                                               const u16* __restrict__ Bw,
                                               float* __restrict__ Cf,
                                               u16* __restrict__ Ch,
                                               int M, int N, int K) {
  __shared__ __align__(16) u16 Asm[128 * 64];
  __shared__ __align__(16) u16 Bsm[128 * 64];
  const int tid = threadIdx.x;
  const int w = tid >> 6, l = tid & 63;
  const int wr = w >> 1, wc = w & 1;
  const int m0 = blockIdx.y * 128, n0 = blockIdx.x * 128;
  const int lr = l >> 3, lc = l & 7, csrc = lc ^ lr;  // pre-swizzled source chunk
  const int laneq = l & 15, laneg = l >> 4;
  f32x4 acc[4][4] = {};
  for (int k0 = 0; k0 < K; k0 += 64) {
    __syncthreads();
#pragma unroll
    for (int c = 0; c < 4; ++c) {
      const int row = c * 32 + w * 8 + lr;
      async16(A + (size_t)(m0 + row) * K + k0 + csrc * 8, &Asm[c * 2048 + w * 512]);
      async16(Bw + (size_t)(n0 + row) * K + k0 + csrc * 8, &Bsm[c * 2048 + w * 512]);
    }
    __syncthreads();
#pragma unroll
    for (int ks = 0; ks < 2; ++ks) {
      f16x8 af[4], bfr[4];
#pragma unroll
      for (int mi = 0; mi < 4; ++mi) {
        const int row = wr * 64 + mi * 16 + laneq;
        const int ch = (ks * 4 + laneg) ^ (row & 7);
        af[mi] = *(const f16x8*)&Asm[row * 64 + ch * 8];
      }
#pragma unroll
      for (int ni = 0; ni < 4; ++ni) {
        const int row = wc * 64 + ni * 16 + laneq;
        const int ch = (ks * 4 + laneg) ^ (row & 7);
        bfr[ni] = *(const f16x8*)&Bsm[row * 64 + ch * 8];
      }
#pragma unroll
      for (int mi = 0; mi < 4; ++mi)
#pragma unroll
        for (int ni = 0; ni < 4; ++ni)
          acc[mi][ni] = MFMA16(af[mi], bfr[ni], acc[mi][ni]);
    }
  }
#pragma unroll
  for (int mi = 0; mi < 4; ++mi)
#pragma unroll
    for (int r = 0; r < 4; ++r) {
      const int gm = m0 + wr * 64 + mi * 16 + laneg * 4 + r;
#pragma unroll
      for (int ni = 0; ni < 4; ++ni) {
        const int gn = n0 + wc * 64 + ni * 16 + laneq;
        if constexpr (OF32) Cf[(size_t)gm * N + gn] = acc[mi][ni][r];
        else                Ch[(size_t)gm * N + gn] = f2h(acc[mi][ni][r]);
      }
    }
}

// ---------------- Flash attention ----------------
// Q,K,V,AO: f16, layout [B*S, 1024] row-major; head h occupies cols h*64..h*64+63.
// Block: 256 thr = 4 waves; 64 q-rows per block (16 per wave); KV tile = 64 keys.
// S^T = mfma(K, Q^T): C col = q = lane&15  -> per-lane scalar softmax state.
// O^T = mfma(V^T, P^T): same col = q; V staged transposed (+XOR swizzle) in LDS.
__global__ __launch_bounds__(256) void attn_fwd(const u16* __restrict__ Qp,
                                                const u16* __restrict__ Kp,
                                                const u16* __restrict__ Vp,
                                                u16* __restrict__ AO) {
  __shared__ __align__(16) u16 Ksm[64 * 64];      // [key][dk], chunk ^= key&7
  __shared__ __align__(16) u16 Vts[64 * 64];      // [dk][key], chunk ^= dk&7
  __shared__ __align__(16) u16 Psm[4][16 * 64];   // per-wave [q][key], chunk ^= q&7
  constexpr float SC = 0.125f * 1.44269504088896340736f;  // scale * log2(e)
  const int tid = threadIdx.x, w = tid >> 6, l = tid & 63;
  const int bh = blockIdx.y, b = bh >> 4, h = bh & 15;
  const int q0 = blockIdx.x * 64;
  const size_t hb = (size_t)b * 4096 * 1024 + (size_t)h * 64;
  const int laneq = l & 15, laneg = l >> 4;
  const int lr = l >> 3, lc = l & 7, csrc = lc ^ lr;
  f16x8 qf[2];
  {
    const u16* qp = Qp + hb + (size_t)(q0 + w * 16 + laneq) * 1024 + laneg * 8;
    qf[0] = *(const f16x8*)qp;
    qf[1] = *(const f16x8*)(qp + 32);
  }
  float m = -1e30f, lsum = 0.f;
  f32x4 acco[4] = {};
  for (int t = 0; t < 64; ++t) {
    const int key0 = t * 64;
    __syncthreads();
    // stage K tile (8KB) via global_load_lds, source pre-swizzled
#pragma unroll
    for (int c = 0; c < 2; ++c) {
      const int key = c * 32 + w * 8 + lr;
      async16(Kp + hb + (size_t)(key0 + key) * 1024 + csrc * 8, &Ksm[c * 2048 + w * 512]);
    }
    // stage V tile transposed through registers: Vts[dk][key], swizzled
#pragma unroll
    for (int i = 0; i < 2; ++i) {
      const int dkc = i * 4 + w;
      union { uint4 u; u16 s[8]; } vv;
      vv.u = *(const uint4*)(Vp + hb + (size_t)(key0 + l) * 1024 + dkc * 8);
#pragma unroll
      for (int j = 0; j < 8; ++j)
        Vts[(dkc * 8 + j) * 64 + (l ^ (j << 3))] = vv.s[j];
    }
    __syncthreads();
    // S^T = K * Q^T  (rows=key, cols=q)
    f32x4 accs[4] = {};
#pragma unroll
    for (int t4 = 0; t4 < 4; ++t4) {
      const int row = t4 * 16 + laneq;
#pragma unroll
      for (int ks = 0; ks < 2; ++ks) {
        const int ch = (ks * 4 + laneg) ^ (row & 7);
        const f16x8 ka = *(const f16x8*)&Ksm[row * 64 + ch * 8];
        accs[t4] = MFMA16(ka, qf[ks], accs[t4]);
      }
    }
    // online softmax; q = laneq, state is per-lane scalar
    float tmax = -1e30f;
#pragma unroll
    for (int t4 = 0; t4 < 4; ++t4)
#pragma unroll
      for (int r = 0; r < 4; ++r) tmax = fmaxf(tmax, accs[t4][r]);
    tmax = fmaxf(tmax, __shfl_xor(tmax, 16));
    tmax = fmaxf(tmax, __shfl_xor(tmax, 32));
    const float mnew = fmaxf(m, tmax);
    const float corr = exp2f((m - mnew) * SC);
    float ps = 0.f;
#pragma unroll
    for (int t4 = 0; t4 < 4; ++t4)
#pragma unroll
      for (int r = 0; r < 4; ++r) {
        const float p = exp2f((accs[t4][r] - mnew) * SC);
        ps += p;
        const int key = t4 * 16 + laneg * 4 + r;
        Psm[w][laneq * 64 + (key ^ ((laneq & 7) << 3))] = f2h(p);
      }
    ps += __shfl_xor(ps, 16);
    ps += __shfl_xor(ps, 32);
    lsum = lsum * corr + ps;
    m = mnew;
#pragma unroll
    for (int t4 = 0; t4 < 4; ++t4)
#pragma unroll
      for (int r = 0; r < 4; ++r) acco[t4][r] *= corr;
    // O^T += V^T * P^T
#pragma unroll
    for (int ks = 0; ks < 2; ++ks) {
      const f16x8 pb = *(const f16x8*)&Psm[w][laneq * 64 + (((ks * 4 + laneg) ^ (laneq & 7)) << 3)];
#pragma unroll
      for (int dt = 0; dt < 4; ++dt) {
        const int dk = dt * 16 + laneq;
        const int ch = (ks * 4 + laneg) ^ (dk & 7);
        const f16x8 va = *(const f16x8*)&Vts[dk * 64 + ch * 8];
        acco[dt] = MFMA16(va, pb, acco[dt]);
      }
    }
  }
  const float rn = 1.0f / lsum;
  const size_t orow = hb + (size_t)(q0 + w * 16 + laneq) * 1024;
#pragma unroll
  for (int dt = 0; dt < 4; ++dt)
#pragma unroll
    for (int r = 0; r < 4; ++r)
      AO[orow + dt * 16 + laneg * 4 + r] = f2h(acco[dt][r] * rn);
}

// ---------------- launch ----------------
extern "C" void kernel_launch(void* const* d_in, const int* in_sizes, int n_in,
                              void* d_out, int out_size, void* d_ws, size_t ws_size,
                              hipStream_t stream) {
  const float* q  = (const float*)d_in[0];
  const float* k  = (const float*)d_in[1];
  const float* v  = (const float*)d_in[2];
  // d_in[3] = mask: no-op in the reference, ignored.
  const float* Wq = (const float*)d_in[4];
  const float* Wk = (const float*)d_in[5];
  const float* Wv = (const float*)d_in[6];
  const float* Wo = (const float*)d_in[7];
  float* out = (float*)d_out;

  char* ws = (char*)d_ws;
  u16* xb  = (u16*)ws;                        // 16 MiB: f16 staging of q/k/v (reused)
  u16* wqb = (u16*)(ws + 16777216);           // 4 x 2 MiB weights
  u16* wkb = wqb + 1048576;
  u16* wvb = wkb + 1048576;
  u16* wob = wvb + 1048576;
  u16* Qp  = (u16*)(ws + 16777216 + 8388608); // 16 MiB each
  u16* Kpp = Qp + 8388608;
  u16* Vpp = Kpp + 8388608;
  u16* AO  = Vpp + 8388608;                   // total ws use: 92,274,688 B

  cvt_f32_f16<<<256, 256, 0, stream>>>(Wq, wqb, 262144);
  cvt_f32_f16<<<256, 256, 0, stream>>>(Wk, wkb, 262144);
  cvt_f32_f16<<<256, 256, 0, stream>>>(Wv, wvb, 262144);
  cvt_f32_f16<<<256, 256, 0, stream>>>(Wo, wob, 262144);

  const dim3 gg(8, 64), gb(256);
  cvt_f32_f16<<<2048, 256, 0, stream>>>(q, xb, 2097152);
  gemm_bt<0><<<gg, gb, 0, stream>>>(xb, wqb, nullptr, Qp, 8192, 1024, 1024);
  cvt_f32_f16<<<2048, 256, 0, stream>>>(k, xb, 2097152);
  gemm_bt<0><<<gg, gb, 0, stream>>>(xb, wkb, nullptr, Kpp, 8192, 1024, 1024);
  cvt_f32_f16<<<2048, 256, 0, stream>>>(v, xb, 2097152);
  gemm_bt<0><<<gg, gb, 0, stream>>>(xb, wvb, nullptr, Vpp, 8192, 1024, 1024);

  attn_fwd<<<dim3(64, 32), gb, 0, stream>>>(Qp, Kpp, Vpp, AO);

  gemm_bt<1><<<gg, gb, 0, stream>>>(AO, wob, out, nullptr, 8192, 1024, 1024);
}

// Round 2
// 367.980 us; speedup vs baseline: 1.3141x; 1.3141x over previous
//
#include <hip/hip_runtime.h>
#include <cstdint>
#include <cstddef>

using u16 = unsigned short;
using u32 = unsigned int;

typedef _Float16 f16x8 __attribute__((ext_vector_type(8)));
typedef float    f32x4 __attribute__((ext_vector_type(4)));
typedef float    f32x16 __attribute__((ext_vector_type(16)));

#define MFMA16(a,b,c) __builtin_amdgcn_mfma_f32_16x16x32_f16((a),(b),(c),0,0,0)
#define MFMA32(a,b,c) __builtin_amdgcn_mfma_f32_32x32x16_f16((a),(b),(c),0,0,0)

__device__ __forceinline__ u16 f2h(float f) {
  return __builtin_bit_cast(u16, (_Float16)f);
}
__device__ __forceinline__ u32 pkrtz(float a, float b) {
  return __builtin_bit_cast(u32, __builtin_amdgcn_cvt_pkrtz(a, b));
}
__device__ __forceinline__ void plswap(u32 &a, u32 &b) {
  asm volatile("v_permlane32_swap_b32 %0, %1" : "+v"(a), "+v"(b));
}
__device__ __forceinline__ void async16(const void* g, void* lds) {
  __builtin_amdgcn_global_load_lds((const __attribute__((address_space(1))) void*)g,
                                   (__attribute__((address_space(3))) void*)lds,
                                   16, 0, 0);
}

// ---------------- fp32 -> fp16 convert ----------------
__global__ __launch_bounds__(256) void cvt_f32_f16(const float* __restrict__ in,
                                                   u16* __restrict__ out, int n4) {
  int i = blockIdx.x * 256 + threadIdx.x;
  const int stride = gridDim.x * 256;
  for (; i < n4; i += stride) {
    const float4 f = reinterpret_cast<const float4*>(in)[i];
    ushort4 o;
    o.x = f2h(f.x); o.y = f2h(f.y); o.z = f2h(f.z); o.w = f2h(f.w);
    reinterpret_cast<ushort4*>(out)[i] = o;
  }
}

// ---------------- GEMM: C[M,N] = A[M,K] * B[N,K]^T (both f16 row-major) ----------------
template <int OF32>
__global__ __launch_bounds__(256) void gemm_bt(const u16* __restrict__ A,
                                               const u16* __restrict__ Bw,
                                               float* __restrict__ Cf,
                                               u16* __restrict__ Ch,
                                               int M, int N, int K) {
  __shared__ __align__(16) u16 Asm[128 * 64];
  __shared__ __align__(16) u16 Bsm[128 * 64];
  const int tid = threadIdx.x;
  const int w = tid >> 6, l = tid & 63;
  const int wr = w >> 1, wc = w & 1;
  const int m0 = blockIdx.y * 128, n0 = blockIdx.x * 128;
  const int lr = l >> 3, lc = l & 7, csrc = lc ^ lr;
  const int laneq = l & 15, laneg = l >> 4;
  f32x4 acc[4][4] = {};
  for (int k0 = 0; k0 < K; k0 += 64) {
    __syncthreads();
#pragma unroll
    for (int c = 0; c < 4; ++c) {
      const int row = c * 32 + w * 8 + lr;
      async16(A + (size_t)(m0 + row) * K + k0 + csrc * 8, &Asm[c * 2048 + w * 512]);
      async16(Bw + (size_t)(n0 + row) * K + k0 + csrc * 8, &Bsm[c * 2048 + w * 512]);
    }
    __syncthreads();
#pragma unroll
    for (int ks = 0; ks < 2; ++ks) {
      f16x8 af[4], bfr[4];
#pragma unroll
      for (int mi = 0; mi < 4; ++mi) {
        const int row = wr * 64 + mi * 16 + laneq;
        const int ch = (ks * 4 + laneg) ^ (row & 7);
        af[mi] = *(const f16x8*)&Asm[row * 64 + ch * 8];
      }
#pragma unroll
      for (int ni = 0; ni < 4; ++ni) {
        const int row = wc * 64 + ni * 16 + laneq;
        const int ch = (ks * 4 + laneg) ^ (row & 7);
        bfr[ni] = *(const f16x8*)&Bsm[row * 64 + ch * 8];
      }
#pragma unroll
      for (int mi = 0; mi < 4; ++mi)
#pragma unroll
        for (int ni = 0; ni < 4; ++ni)
          acc[mi][ni] = MFMA16(af[mi], bfr[ni], acc[mi][ni]);
    }
  }
#pragma unroll
  for (int mi = 0; mi < 4; ++mi)
#pragma unroll
    for (int r = 0; r < 4; ++r) {
      const int gm = m0 + wr * 64 + mi * 16 + laneg * 4 + r;
#pragma unroll
      for (int ni = 0; ni < 4; ++ni) {
        const int gn = n0 + wc * 64 + ni * 16 + laneq;
        if constexpr (OF32) Cf[(size_t)gm * N + gn] = acc[mi][ni][r];
        else                Ch[(size_t)gm * N + gn] = f2h(acc[mi][ni][r]);
      }
    }
}

// ---------------- V transpose: Vp[b*4096+s][h*64+dk] -> VT[bh][dk][s] ----------------
__global__ __launch_bounds__(256) void transpose_v(const u16* __restrict__ Vp,
                                                   u16* __restrict__ VT) {
  __shared__ u16 t[64 * 66];
  const int tid = threadIdx.x;
  const int s0 = blockIdx.x * 64, bh = blockIdx.y;
  const int b = bh >> 4, h = bh & 15;
  const int r = tid >> 2;
  const u16* src = Vp + (size_t)(b * 4096 + s0 + r) * 1024 + h * 64;
#pragma unroll
  for (int i = 0; i < 2; ++i) {
    const int c = (tid & 3) + i * 4;
    union { uint4 u; u32 ww[4]; } vv;
    vv.u = *(const uint4*)(src + c * 8);
#pragma unroll
    for (int j = 0; j < 4; ++j)
      *(u32*)&t[r * 66 + c * 8 + j * 2] = vv.ww[j];
  }
  __syncthreads();
  const int dk = tid >> 2;
  u16* dst = VT + ((size_t)bh * 64 + dk) * 4096 + s0;
#pragma unroll
  for (int i = 0; i < 2; ++i) {
    const int sc = (tid & 3) + i * 4;
    union { uint4 u; u16 s[8]; } o;
#pragma unroll
    for (int j = 0; j < 8; ++j) o.s[j] = t[(sc * 8 + j) * 66 + dk];
    *(uint4*)(dst + sc * 8) = o.u;
  }
}

// ---------------- Flash attention, 32x32 MFMA, in-register softmax ----------------
// Block = 4 waves x 64 q-rows = 256 q-rows. KV staged in 64-key tiles (dbuf).
// S^T = mfma32(K, Q^T): col=q=lane&31 -> per-lane scalar m/l.
// P -> B-frag in-register via cvt_pkrtz + permlane32_swap (no LDS for P).
// O^T = mfma32(V^T, P^T); V^T staged from pre-transposed VT via global_load_lds.
__global__ __launch_bounds__(256, 2) void attn_fwd(const u16* __restrict__ Qp,
                                                   const u16* __restrict__ Kp,
                                                   const u16* __restrict__ VT,
                                                   u16* __restrict__ AO) {
  union SM {
    struct { u16 K[2][4096]; u16 V[2][4096]; } st;   // 32 KiB staging (dbuf)
    u16 osm[4][64 * 72];                              // 36 KiB epilogue transpose
  };
  __shared__ __align__(16) SM sm;
  constexpr float SC = 0.125f * 1.44269504088896340736f;  // scale * log2(e)
  const int tid = threadIdx.x, w = tid >> 6, l = tid & 63;
  const int l31 = l & 31, hi = l >> 5, l7 = l & 7, lr = l >> 3;
  const int csrc = l7 ^ lr;
  // XCD-aware swizzle: 16 q-blocks of one (b,h) land on one XCD (4 heads/XCD L2).
  const int bid = blockIdx.x;
  const int slot = bid >> 3;
  const int bh = (bid & 7) * 4 + (slot >> 4), qx = slot & 15;
  const int b = bh >> 4, h = bh & 15;
  const int q0 = qx * 256;
  const size_t hb = (size_t)b * 4096 * 1024 + (size_t)h * 64;
  const u16* Kh = Kp + hb;
  const u16* Vh = VT + (size_t)bh * 64 * 4096;

  // Q fragments (held in regs): B-operand, col=q=lane&31, k=dk=hi*8+j
  f16x8 qf[2][4];
#pragma unroll
  for (int qs = 0; qs < 2; ++qs) {
    const u16* qp = Qp + hb + (size_t)(q0 + w * 64 + qs * 32 + l31) * 1024 + hi * 8;
#pragma unroll
    for (int kk = 0; kk < 4; ++kk) qf[qs][kk] = *(const f16x8*)(qp + kk * 16);
  }

  float m[2] = {-3e38f, -3e38f}, lsum[2] = {0.f, 0.f};
  f32x16 acc[2][2];
#pragma unroll
  for (int qs = 0; qs < 2; ++qs)
#pragma unroll
    for (int ds = 0; ds < 2; ++ds)
#pragma unroll
      for (int r = 0; r < 16; ++r) acc[qs][ds][r] = 0.f;

  // stage tile 0 into buf 0
#pragma unroll
  for (int i = 0; i < 2; ++i) {
    const int rowb = (i * 4 + w) * 8 + lr;
    async16(Kh + (size_t)rowb * 1024 + csrc * 8, &sm.st.K[0][(i * 4 + w) * 512]);
    async16(Vh + (size_t)rowb * 4096 + csrc * 8, &sm.st.V[0][(i * 4 + w) * 512]);
  }

  for (int t = 0; t < 64; ++t) {
    const int cur = t & 1;
    __syncthreads();  // drains vmcnt: tile t staged; all waves done reading buf cur^1
    if (t + 1 < 64) {
      const int key0 = (t + 1) * 64;
#pragma unroll
      for (int i = 0; i < 2; ++i) {
        const int rowb = (i * 4 + w) * 8 + lr;
        async16(Kh + (size_t)(key0 + rowb) * 1024 + csrc * 8, &sm.st.K[cur ^ 1][(i * 4 + w) * 512]);
        async16(Vh + (size_t)rowb * 4096 + key0 + csrc * 8, &sm.st.V[cur ^ 1][(i * 4 + w) * 512]);
      }
    }
    const u16* Ks = sm.st.K[cur];
    const u16* Vs = sm.st.V[cur];
#pragma unroll
    for (int kt = 0; kt < 2; ++kt) {
      // ---- QK^T for 32-key subtile, both q-subtiles share K-frag ----
      f32x16 sv[2];
#pragma unroll
      for (int qs = 0; qs < 2; ++qs)
#pragma unroll
        for (int r = 0; r < 16; ++r) sv[qs][r] = 0.f;
#pragma unroll
      for (int kk = 0; kk < 4; ++kk) {
        const f16x8 kf = *(const f16x8*)&Ks[(kt * 32 + l31) * 64 + (((kk * 2 + hi) ^ l7) << 3)];
        sv[0] = MFMA32(kf, qf[0][kk], sv[0]);
        sv[1] = MFMA32(kf, qf[1][kk], sv[1]);
      }
      // ---- online softmax (per-lane scalar state; q = lane&31) ----
      f16x8 pf[2][2];
#pragma unroll
      for (int qs = 0; qs < 2; ++qs) {
        float tmax = sv[qs][0];
#pragma unroll
        for (int r = 1; r < 16; ++r) tmax = fmaxf(tmax, sv[qs][r]);
        tmax = fmaxf(tmax, __shfl_xor(tmax, 32));
        if (__any(tmax > m[qs] + 16.f)) {   // defer-max (T13)
          const float mn = fmaxf(m[qs], tmax);
          const float corr = exp2f((m[qs] - mn) * SC);
          lsum[qs] *= corr;
#pragma unroll
          for (int ds = 0; ds < 2; ++ds)
#pragma unroll
            for (int r = 0; r < 16; ++r) acc[qs][ds][r] *= corr;
          m[qs] = mn;
        }
        const float msc = m[qs] * SC;
        float ps = 0.f;
#pragma unroll
        for (int r = 0; r < 16; ++r) {
          const float pp = exp2f(sv[qs][r] * SC - msc);
          ps += pp;
          sv[qs][r] = pp;
        }
        ps += __shfl_xor(ps, 32);
        lsum[qs] += ps;
        // ---- P -> PV B-fragment, in-register (cvt_pkrtz + permlane32_swap) ----
#pragma unroll
        for (int half = 0; half < 2; ++half) {
          const int rb = half * 8;
          u32 a0 = pkrtz(sv[qs][rb + 0], sv[qs][rb + 1]);
          u32 a1 = pkrtz(sv[qs][rb + 2], sv[qs][rb + 3]);
          u32 b0 = pkrtz(sv[qs][rb + 4], sv[qs][rb + 5]);
          u32 b1 = pkrtz(sv[qs][rb + 6], sv[qs][rb + 7]);
          plswap(a0, b0);
          plswap(a1, b1);
          union { u32 ww[4]; f16x8 v; } uu;
          uu.ww[0] = a0; uu.ww[1] = a1; uu.ww[2] = b0; uu.ww[3] = b1;
          pf[qs][half] = uu.v;
        }
      }
      // ---- PV: O^T += V^T * P^T, V-frag shared by both q-subtiles ----
#pragma unroll
      for (int ds = 0; ds < 2; ++ds)
#pragma unroll
        for (int half = 0; half < 2; ++half) {
          const f16x8 vf = *(const f16x8*)&Vs[(ds * 32 + l31) * 64 + (((kt * 4 + half * 2 + hi) ^ l7) << 3)];
          acc[0][ds] = MFMA32(vf, pf[0][half], acc[0][ds]);
          acc[1][ds] = MFMA32(vf, pf[1][half], acc[1][ds]);
        }
    }
  }
  // ---- epilogue: per-wave LDS transpose O^T -> coalesced AO write ----
  __syncthreads();
#pragma unroll
  for (int qs = 0; qs < 2; ++qs) {
    const float rn = 1.f / lsum[qs];
#pragma unroll
    for (int ds = 0; ds < 2; ++ds)
#pragma unroll
      for (int g = 0; g < 4; ++g) {
        uint2 val;
        val.x = pkrtz(acc[qs][ds][4 * g + 0] * rn, acc[qs][ds][4 * g + 1] * rn);
        val.y = pkrtz(acc[qs][ds][4 * g + 2] * rn, acc[qs][ds][4 * g + 3] * rn);
        *(uint2*)&sm.osm[w][(qs * 32 + l31) * 72 + ds * 32 + g * 8 + hi * 4] = val;
      }
  }
  asm volatile("s_waitcnt lgkmcnt(0)" ::: "memory");
#pragma unroll
  for (int i = 0; i < 8; ++i) {
    const int row = lr + i * 8;
    const uint4 vv = *(const uint4*)&sm.osm[w][row * 72 + l7 * 8];
    *(uint4*)(AO + hb + (size_t)(q0 + w * 64 + row) * 1024 + l7 * 8) = vv;
  }
}

// ---------------- launch ----------------
extern "C" void kernel_launch(void* const* d_in, const int* in_sizes, int n_in,
                              void* d_out, int out_size, void* d_ws, size_t ws_size,
                              hipStream_t stream) {
  const float* q  = (const float*)d_in[0];
  const float* k  = (const float*)d_in[1];
  const float* v  = (const float*)d_in[2];
  // d_in[3] = mask: no-op in the reference, ignored.
  const float* Wq = (const float*)d_in[4];
  const float* Wk = (const float*)d_in[5];
  const float* Wv = (const float*)d_in[6];
  const float* Wo = (const float*)d_in[7];
  float* out = (float*)d_out;

  char* ws = (char*)d_ws;
  u16* xb  = (u16*)ws;                        // 16 MiB: f16 staging of q/k/v, then VT
  u16* wqb = (u16*)(ws + 16777216);           // 4 x 2 MiB weights
  u16* wkb = wqb + 1048576;
  u16* wvb = wkb + 1048576;
  u16* wob = wvb + 1048576;
  u16* Qp  = (u16*)(ws + 16777216 + 8388608); // 16 MiB each
  u16* Kpp = Qp + 8388608;
  u16* Vpp = Kpp + 8388608;
  u16* AO  = Vpp + 8388608;                   // total ws use: 92,274,688 B

  cvt_f32_f16<<<256, 256, 0, stream>>>(Wq, wqb, 262144);
  cvt_f32_f16<<<256, 256, 0, stream>>>(Wk, wkb, 262144);
  cvt_f32_f16<<<256, 256, 0, stream>>>(Wv, wvb, 262144);
  cvt_f32_f16<<<256, 256, 0, stream>>>(Wo, wob, 262144);

  const dim3 gg(8, 64), gb(256);
  cvt_f32_f16<<<2048, 256, 0, stream>>>(q, xb, 2097152);
  gemm_bt<0><<<gg, gb, 0, stream>>>(xb, wqb, nullptr, Qp, 8192, 1024, 1024);
  cvt_f32_f16<<<2048, 256, 0, stream>>>(k, xb, 2097152);
  gemm_bt<0><<<gg, gb, 0, stream>>>(xb, wkb, nullptr, Kpp, 8192, 1024, 1024);
  cvt_f32_f16<<<2048, 256, 0, stream>>>(v, xb, 2097152);
  gemm_bt<0><<<gg, gb, 0, stream>>>(xb, wvb, nullptr, Vpp, 8192, 1024, 1024);

  transpose_v<<<dim3(64, 32), gb, 0, stream>>>(Vpp, xb);  // VT into xb (16 MiB)

  attn_fwd<<<512, gb, 0, stream>>>(Qp, Kpp, xb, AO);

  gemm_bt<1><<<gg, gb, 0, stream>>>(AO, wob, out, nullptr, 8192, 1024, 1024);
}